// Round 1
// baseline (307.606 us; speedup 1.0000x reference)
//
#include <hip/hip_runtime.h>
#include <cstdint>
#include <cstddef>

#define NH  16
#define HD  64
#define DM  1024
#define SB  2048
#define BBB 2
#define WIN 512

typedef _Float16 half8  __attribute__((ext_vector_type(8)));
typedef float    f32x4  __attribute__((ext_vector_type(4)));

// global_load_lds: LDS dest must be WAVE-UNIFORM (hw adds lane*16); global src is per-lane.
#define GLL16(gp, lp) __builtin_amdgcn_global_load_lds( \
    (const __attribute__((address_space(1))) void*)(gp), \
    (__attribute__((address_space(3))) void*)(lp), 16, 0, 0)

// ---------------- convert x: f32 -> f16 ----------------
__global__ void k_cvt_x(const float* __restrict__ x, _Float16* __restrict__ xh) {
  const int i = (blockIdx.x * 256 + threadIdx.x) * 8;
  const float4 a = *(const float4*)(x + i);
  const float4 b = *(const float4*)(x + i + 4);
  half8 o = { (_Float16)a.x, (_Float16)a.y, (_Float16)a.z, (_Float16)a.w,
              (_Float16)b.x, (_Float16)b.y, (_Float16)b.z, (_Float16)b.w };
  *(half8*)(xh + i) = o;
}

// ------- convert+transpose weights: W[k][n] f32 -> Wt[z][n][k] f16 -------
__global__ void k_cvt_w(const float* __restrict__ Wq, const float* __restrict__ Wk,
                        const float* __restrict__ Wv, const float* __restrict__ Wo,
                        _Float16* __restrict__ Wt) {
  const int z = blockIdx.z;
  const float* src = (z == 0) ? Wq : (z == 1) ? Wk : (z == 2) ? Wv : Wo;
  _Float16* dst = Wt + (size_t)z * DM * DM;
  const int k0 = blockIdx.x * 64, n0 = blockIdx.y * 64;
  __shared__ float t[64][68];
  const int tid = threadIdx.x;
  #pragma unroll
  for (int i = 0; i < 4; ++i) {
    const int idx = i * 1024 + tid * 4;
    const int r = idx >> 6, c = idx & 63;
    const float4 v = *(const float4*)(src + (size_t)(k0 + r) * DM + n0 + c);
    *(float4*)(&t[r][c]) = v;
  }
  __syncthreads();
  #pragma unroll
  for (int i = 0; i < 4; ++i) {
    const int idx = i * 1024 + tid * 4;
    const int nr = idx >> 6, kc = idx & 63;
    _Float16 o0 = (_Float16)t[kc + 0][nr];
    _Float16 o1 = (_Float16)t[kc + 1][nr];
    _Float16 o2 = (_Float16)t[kc + 2][nr];
    _Float16 o3 = (_Float16)t[kc + 3][nr];
    _Float16* p = dst + (size_t)(n0 + nr) * DM + k0 + kc;
    p[0] = o0; p[1] = o1; p[2] = o2; p[3] = o3;
  }
}

// ---------------- GEMM: C[M,N] = A[M,K]h * Wt[N,K]h + bias; M=4096,N=K=1024 ----------------
template<bool F32OUT>
__global__ __launch_bounds__(256) void k_gemm(
    const _Float16* __restrict__ A, const _Float16* __restrict__ Wt,
    const float* __restrict__ b0, const float* __restrict__ b1, const float* __restrict__ b2,
    void* __restrict__ outv, float scale0)
{
  __shared__ _Float16 As[128 * 64];
  __shared__ _Float16 Bs[128 * 64];
  const int z = blockIdx.z;
  const _Float16* Wz = Wt + (size_t)z * DM * DM;
  const float* bias = (z == 0) ? b0 : (z == 1) ? b1 : b2;
  const float scale = (z == 0) ? scale0 : 1.0f;
  const int m0 = blockIdx.x * 128, n0 = blockIdx.y * 128;
  const int tid = threadIdx.x, lane = tid & 63, wid = tid >> 6;
  const int g = lane >> 4, li = lane & 15;
  const int wr = (wid & 1) * 64, wc = (wid >> 1) * 64;

  f32x4 acc[4][4] = {};

  for (int kt = 0; kt < 16; ++kt) {
    const int kb = kt * 64;
    #pragma unroll
    for (int i = 0; i < 4; ++i) {
      const int c = wid + 4 * i;                 // 1KB chunk id
      const int off = c * 1024 + lane * 16;      // linear byte offset in tile
      const int r = off >> 7;                    // tile row (128B rows)
      const int cb = off & 127;                  // linear byte-in-row
      const int sc_ = cb ^ ((r & 7) << 4);       // inverse-swizzled source column
      GLL16(A  + (size_t)(m0 + r) * DM + kb + (sc_ >> 1), (char*)As + c * 1024);
      GLL16(Wz + (size_t)(n0 + r) * DM + kb + (sc_ >> 1), (char*)Bs + c * 1024);
    }
    __syncthreads();
    #pragma unroll
    for (int kk = 0; kk < 2; ++kk) {
      half8 af[4], bf[4];
      #pragma unroll
      for (int mi = 0; mi < 4; ++mi) {
        const int r = wr + mi * 16 + li;
        const int cbyte = (kk * 64 + g * 16) ^ ((r & 7) << 4);
        af[mi] = *(const half8*)((const char*)As + r * 128 + cbyte);
      }
      #pragma unroll
      for (int ni = 0; ni < 4; ++ni) {
        const int r = wc + ni * 16 + li;
        const int cbyte = (kk * 64 + g * 16) ^ ((r & 7) << 4);
        bf[ni] = *(const half8*)((const char*)Bs + r * 128 + cbyte);
      }
      #pragma unroll
      for (int mi = 0; mi < 4; ++mi)
        #pragma unroll
        for (int ni = 0; ni < 4; ++ni)
          acc[mi][ni] = __builtin_amdgcn_mfma_f32_16x16x32_f16(af[mi], bf[ni], acc[mi][ni], 0, 0, 0);
    }
    __syncthreads();
  }

  float bv[4];
  #pragma unroll
  for (int ni = 0; ni < 4; ++ni) bv[ni] = bias[n0 + wc + ni * 16 + li];
  #pragma unroll
  for (int mi = 0; mi < 4; ++mi)
    #pragma unroll
    for (int ni = 0; ni < 4; ++ni)
      #pragma unroll
      for (int reg = 0; reg < 4; ++reg) {
        const int row = m0 + wr + mi * 16 + g * 4 + reg;
        const int col = n0 + wc + ni * 16 + li;
        const float v = (acc[mi][ni][reg] + bv[ni]) * scale;
        if (F32OUT) ((float*)outv)[(size_t)row * DM + col] = v;
        else ((_Float16*)outv + (size_t)z * 4096 * 1024)[(size_t)row * DM + col] = (_Float16)v;
      }
}

// ---------------- transpose V: V[b*S+s][h*64+d] -> Vt[(b*16+h)*64+d][s] ----------------
__global__ void k_trans_v(const _Float16* __restrict__ V, _Float16* __restrict__ Vt) {
  const int s0 = blockIdx.x * 64, h = blockIdx.y, b = blockIdx.z;
  __shared__ _Float16 t[64][72];
  const int tid = threadIdx.x;
  #pragma unroll
  for (int i = 0; i < 2; ++i) {
    const int off = i * 4096 + tid * 16;
    const int r = off >> 7, cb = (off & 127) >> 1;
    half8 v = *(const half8*)(V + (size_t)(b * SB + s0 + r) * DM + h * HD + cb);
    *(half8*)(&t[r][cb]) = v;
  }
  __syncthreads();
  #pragma unroll
  for (int i = 0; i < 2; ++i) {
    const int off = i * 4096 + tid * 16;
    const int d = off >> 7, sb = (off & 127) >> 1;
    half8 v;
    #pragma unroll
    for (int j = 0; j < 8; ++j) v[j] = t[sb + j][d];
    *(half8*)(Vt + (size_t)((b * NH + h) * HD + d) * SB + s0 + sb) = v;
  }
}

// ---------------- sliding-window attention ----------------
__global__ __launch_bounds__(256) void k_attn(
    const _Float16* __restrict__ Q, const _Float16* __restrict__ K,
    const _Float16* __restrict__ Vt, float* __restrict__ Wout,
    _Float16* __restrict__ attb)
{
  __shared__ float pw_all[4][16][36];
  const int b = blockIdx.z, h = blockIdx.y;
  const int tid = threadIdx.x, lane = tid & 63, wid = tid >> 6;
  const int g = lane >> 4, li = lane & 15;
  const int t0 = blockIdx.x * 64 + wid * 16;
  float (*pw)[36] = pw_all[wid];

  half8 qf[2];
  #pragma unroll
  for (int kk = 0; kk < 2; ++kk)
    qf[kk] = *(const half8*)(Q + (size_t)(b * SB + t0 + li) * DM + h * HD + kk * 32 + g * 8);

  const int ktq = t0 >> 4;
  const int kt_lo = ktq - 32;

  float sc[34][4];
  #pragma unroll
  for (int it = 0; it < 34; ++it) {
    const int kt = kt_lo + it;
    if (it == 33 || kt < 0) {
      #pragma unroll
      for (int r = 0; r < 4; ++r) sc[it][r] = -1e30f;
      continue;
    }
    f32x4 a = {0.f, 0.f, 0.f, 0.f};
    #pragma unroll
    for (int kk = 0; kk < 2; ++kk) {
      half8 kf = *(const half8*)(K + (size_t)(b * SB + kt * 16 + li) * DM + h * HD + kk * 32 + g * 8);
      a = __builtin_amdgcn_mfma_f32_16x16x32_f16(qf[kk], kf, a, 0, 0, 0);
    }
    #pragma unroll
    for (int r = 0; r < 4; ++r) {
      const int i = t0 + g * 4 + r;
      const int j = kt * 16 + li;
      const bool keep = (j <= i) && (i - j < WIN);
      sc[it][r] = keep ? a[r] : -1e30f;
    }
  }

  float rinv[4];
  #pragma unroll
  for (int r = 0; r < 4; ++r) {
    float m = sc[0][r];
    #pragma unroll
    for (int it = 1; it < 34; ++it) m = fmaxf(m, sc[it][r]);
    m = fmaxf(m, __shfl_xor(m, 1));
    m = fmaxf(m, __shfl_xor(m, 2));
    m = fmaxf(m, __shfl_xor(m, 4));
    m = fmaxf(m, __shfl_xor(m, 8));
    float s = 0.f;
    #pragma unroll
    for (int it = 0; it < 34; ++it) {
      const float p = __expf(sc[it][r] - m);
      sc[it][r] = p;
      s += p;
    }
    s += __shfl_xor(s, 1);
    s += __shfl_xor(s, 2);
    s += __shfl_xor(s, 4);
    s += __shfl_xor(s, 8);
    rinv[r] = 1.0f / s;
  }

  // write normalized window weights (masked entries are exact 0, matching ref underflow)
  float* wb = Wout + (size_t)(b * NH + h) * SB * SB;
  #pragma unroll
  for (int it = 0; it < 33; ++it) {
    const int kt = kt_lo + it;
    if (kt < 0) continue;
    const int j = kt * 16 + li;
    #pragma unroll
    for (int r = 0; r < 4; ++r) {
      const int i = t0 + g * 4 + r;
      wb[(size_t)i * SB + j] = sc[it][r] * rinv[r];
    }
  }
  // zero-fill outside the computed band
  {
    const int lo = kt_lo > 0 ? kt_lo * 16 : 0;
    const int hi = t0 + 16;
    for (int r = 0; r < 16; ++r) {
      float* wr_ = wb + (size_t)(t0 + r) * SB;
      for (int c = lane * 4; c < lo; c += 256)
        *(float4*)(wr_ + c) = make_float4(0.f, 0.f, 0.f, 0.f);
      for (int c = hi + lane * 4; c < SB; c += 256)
        *(float4*)(wr_ + c) = make_float4(0.f, 0.f, 0.f, 0.f);
    }
  }

  // PV: attended = P(16 x 528+pad) * V(... x 64) via LDS relayout of P
  const _Float16* vb = Vt + (size_t)(b * NH + h) * HD * SB;
  f32x4 oacc[4] = {};
  #pragma unroll
  for (int c = 0; c < 17; ++c) {
    if (kt_lo + 2 * c + 1 < 0) continue;
    #pragma unroll
    for (int hf = 0; hf < 2; ++hf) {
      const int it = 2 * c + hf;
      #pragma unroll
      for (int r = 0; r < 4; ++r)
        pw[g * 4 + r][hf * 16 + li] = sc[it][r];
    }
    asm volatile("s_waitcnt lgkmcnt(0)" ::: "memory");
    const float4 p0 = *(const float4*)(&pw[li][g * 8]);
    const float4 p1 = *(const float4*)(&pw[li][g * 8 + 4]);
    half8 pa = { (_Float16)p0.x, (_Float16)p0.y, (_Float16)p0.z, (_Float16)p0.w,
                 (_Float16)p1.x, (_Float16)p1.y, (_Float16)p1.z, (_Float16)p1.w };
    int jb = (kt_lo + 2 * c) * 16 + g * 8;
    jb = jb < 0 ? 0 : (jb > SB - 8 ? SB - 8 : jb);   // clamped; p==0 there anyway
    #pragma unroll
    for (int dt = 0; dt < 4; ++dt) {
      half8 vf = *(const half8*)(vb + (size_t)(dt * 16 + li) * SB + jb);
      oacc[dt] = __builtin_amdgcn_mfma_f32_16x16x32_f16(pa, vf, oacc[dt], 0, 0, 0);
    }
  }
  #pragma unroll
  for (int dt = 0; dt < 4; ++dt)
    #pragma unroll
    for (int r = 0; r < 4; ++r)
      attb[(size_t)(b * SB + t0 + g * 4 + r) * DM + h * HD + dt * 16 + li] =
          (_Float16)(oacc[dt][r] * rinv[r]);
}

extern "C" void kernel_launch(void* const* d_in, const int* in_sizes, int n_in,
                              void* d_out, int out_size, void* d_ws, size_t ws_size,
                              hipStream_t stream) {
  (void)in_sizes; (void)n_in; (void)out_size; (void)ws_size;
  const float* x  = (const float*)d_in[0];
  const float* Wq = (const float*)d_in[1];
  const float* bq = (const float*)d_in[2];
  const float* Wk = (const float*)d_in[3];
  const float* bk = (const float*)d_in[4];
  const float* Wv = (const float*)d_in[5];
  const float* bv = (const float*)d_in[6];
  const float* Wo = (const float*)d_in[7];
  const float* bo = (const float*)d_in[8];

  char* ws = (char*)d_ws;
  _Float16* xh   = (_Float16*)(ws);                      // 8 MB
  _Float16* Wt   = (_Float16*)(ws + (size_t)8  * 1048576); // 8 MB (4x 1024x1024 f16, N-major)
  _Float16* QKV  = (_Float16*)(ws + (size_t)16 * 1048576); // 24 MB
  _Float16* Vt   = (_Float16*)(ws + (size_t)40 * 1048576); // 8 MB
  _Float16* attb = (_Float16*)(ws + (size_t)48 * 1048576); // 8 MB

  float* out = (float*)d_out;
  float* Wattn = out + (size_t)BBB * SB * DM;  // attention-weights output region

  k_cvt_x<<<dim3(2048), dim3(256), 0, stream>>>(x, xh);
  k_cvt_w<<<dim3(16, 16, 4), dim3(256), 0, stream>>>(Wq, Wk, Wv, Wo, Wt);
  k_gemm<false><<<dim3(32, 8, 3), dim3(256), 0, stream>>>(xh, Wt, bq, bk, bv, (void*)QKV, 0.125f);
  k_trans_v<<<dim3(32, 16, 2), dim3(256), 0, stream>>>(QKV + (size_t)2 * 4096 * 1024, Vt);
  k_attn<<<dim3(32, 16, 2), dim3(256), 0, stream>>>(QKV, QKV + (size_t)4096 * 1024, Vt, Wattn, attb);
  k_gemm<true><<<dim3(32, 8, 1), dim3(256), 0, stream>>>(attb, Wt + (size_t)3 * DM * DM, bo, bo, bo, (void*)out, 1.0f);
}